// Round 4
// baseline (256.751 us; speedup 1.0000x reference)
//
#include <hip/hip_runtime.h>

#define DEVINL __device__ __forceinline__

typedef unsigned short u16;
typedef __attribute__((ext_vector_type(4))) short s16x4;
typedef __attribute__((ext_vector_type(8))) short s16x8;
typedef __attribute__((ext_vector_type(4))) float f32x4;

static constexpr int Bb = 4, Tt = 2048, Cc = 1024, Hh = 16, Dd = 64;
static constexpr int Mm = Bb * Tt;  // 8192
static constexpr int KK = Cc;       // 1024

DEVINL float bf2f(u16 u) { return __uint_as_float(((unsigned)u) << 16); }
DEVINL u16 f2bf(float f) {
  unsigned b = __float_as_uint(f);
  b += 0x7fff + ((b >> 16) & 1);  // RNE
  return (u16)(b >> 16);
}

#define GLDS(gsrc, ldst) \
  __builtin_amdgcn_global_load_lds((const __attribute__((address_space(1))) void*)(gsrc), \
                                   (__attribute__((address_space(3))) void*)(ldst), 16, 0, 0)

// ---------------- f32 -> bf16 convert (x4 vectorized) ----------------
__global__ void cvt_bf16(const float* __restrict__ src, u16* __restrict__ dst, int n4) {
  int i = blockIdx.x * blockDim.x + threadIdx.x;
  int st = gridDim.x * blockDim.x;
  for (int g = i; g < n4; g += st) {
    float4 v = ((const float4*)src)[g];
    uint2 o;
    o.x = (unsigned)f2bf(v.x) | ((unsigned)f2bf(v.y) << 16);
    o.y = (unsigned)f2bf(v.z) | ((unsigned)f2bf(v.w) << 16);
    ((uint2*)dst)[g] = o;
  }
}

// ---------------- 4 weight converts in one launch ----------------
struct Cvt4Args { const float* s[4]; u16* d[4]; };
__global__ void cvt4(Cvt4Args a, int n4) {
  const float* __restrict__ src = a.s[blockIdx.y];
  u16* __restrict__ dst = a.d[blockIdx.y];
  int i = blockIdx.x * blockDim.x + threadIdx.x;
  int st = gridDim.x * blockDim.x;
  for (int g = i; g < n4; g += st) {
    float4 v = ((const float4*)src)[g];
    uint2 o;
    o.x = (unsigned)f2bf(v.x) | ((unsigned)f2bf(v.y) << 16);
    o.y = (unsigned)f2bf(v.z) | ((unsigned)f2bf(v.w) << 16);
    ((uint2*)dst)[g] = o;
  }
}

// ---------------- RoPE in-place on q,k; Q pre-scaled by 0.125*log2(e) ----------------
__global__ void rope_kernel(u16* __restrict__ q, u16* __restrict__ k,
                            const float* __restrict__ cache) {
  const float CS = 0.18033688f;  // 0.125 * log2(e) folded into Q
  const int total = Bb * Hh * Tt * 8;  // groups of 8 elems
  int i = blockIdx.x * blockDim.x + threadIdx.x;
  int st = gridDim.x * blockDim.x;
  for (int g = i; g < total; g += st) {
    int off = g * 8;
    int t = (off >> 6) & (Tt - 1);
    int d0 = off & 63;
    const float* cp = cache + t * 64 + d0;  // (T, 32, 2) interleaved cos/sin
    float4 c0 = *(const float4*)cp;
    float4 c1 = *(const float4*)(cp + 4);
    float cs[8] = {c0.x, c0.y, c0.z, c0.w, c1.x, c1.y, c1.z, c1.w};
    s16x8 qv = *(s16x8*)(q + off);
    s16x8 kv = *(s16x8*)(k + off);
    s16x8 qo, ko;
#pragma unroll
    for (int p = 0; p < 4; ++p) {
      float c = cs[2 * p], s = cs[2 * p + 1];
      float a = bf2f((u16)qv[2 * p]), b = bf2f((u16)qv[2 * p + 1]);
      qo[2 * p] = (short)f2bf((a * c - b * s) * CS);
      qo[2 * p + 1] = (short)f2bf((a * s + b * c) * CS);
      a = bf2f((u16)kv[2 * p]); b = bf2f((u16)kv[2 * p + 1]);
      ko[2 * p] = (short)f2bf(a * c - b * s);
      ko[2 * p + 1] = (short)f2bf(a * s + b * c);
    }
    *(s16x8*)(q + off) = qo;
    *(s16x8*)(k + off) = ko;
  }
}

// ---------------- bf16 GEMM: out = A(8192x1024) @ W^T + bias ----------------
// glds staging, pre-swizzled source, 2-barrier loop.
// MODE 0: z=0,1 -> bf16 (B,H,T,D); z=2 -> bf16 (B,H,D,T) transposed (for attn V)
// MODE 1: f32 flat (M x C)
struct GemmArgs {
  const u16* A;
  const u16* W[3];
  const float* bias[3];
  void* out[3];
};

template <int MODE>
__global__ __launch_bounds__(256) void gemm_bt(GemmArgs args) {
  __shared__ __align__(16) u16 As[128 * 64];
  __shared__ __align__(16) u16 Bs[128 * 64];
  const int z = blockIdx.z;
  const u16* __restrict__ A = args.A;
  const u16* __restrict__ Wt = args.W[z];
  const float* __restrict__ bias = args.bias[z];
  const int tid = threadIdx.x, w = tid >> 6, l = tid & 63;
  const int lr = l & 15, lg = l >> 4;
  const int m0 = blockIdx.x * 128, n0 = blockIdx.y * 128;
  const int wr = w >> 1, wc = w & 1;
  f32x4 zero = {0.f, 0.f, 0.f, 0.f};
  f32x4 acc[4][4];
#pragma unroll
  for (int i = 0; i < 4; ++i)
#pragma unroll
    for (int j = 0; j < 4; ++j) acc[i][j] = zero;

  // glds staging: LDS slot (row, c8) <- global col8 (c8 ^ (row&7)); row&7 == l>>3
  const int srow = l >> 3;                     // 0..7
  const int scolsw = ((l & 7) ^ (l >> 3)) * 8; // pre-swizzled source col (elems)

  for (int k0 = 0; k0 < KK; k0 += 64) {
#pragma unroll
    for (int i = 0; i < 4; ++i) {
      int row = i * 32 + w * 8 + srow;
      GLDS(A + (size_t)(m0 + row) * KK + k0 + scolsw, &As[(i * 32 + w * 8) * 64]);
      GLDS(Wt + (size_t)(n0 + row) * KK + k0 + scolsw, &Bs[(i * 32 + w * 8) * 64]);
    }
    __syncthreads();  // drains vmcnt -> tiles ready
#pragma unroll
    for (int kk = 0; kk < 2; ++kk) {
      s16x8 af[4], bfr[4];
#pragma unroll
      for (int i = 0; i < 4; ++i)
        af[i] = *(const s16x8*)&As[(wr * 64 + i * 16 + lr) * 64 +
                                   ((kk * 32 + lg * 8) ^ ((lr & 7) << 3))];
#pragma unroll
      for (int j = 0; j < 4; ++j)
        bfr[j] = *(const s16x8*)&Bs[(wc * 64 + j * 16 + lr) * 64 +
                                    ((kk * 32 + lg * 8) ^ ((lr & 7) << 3))];
#pragma unroll
      for (int i = 0; i < 4; ++i)
#pragma unroll
        for (int j = 0; j < 4; ++j)
          acc[i][j] = __builtin_amdgcn_mfma_f32_16x16x32_bf16(af[i], bfr[j], acc[i][j], 0, 0, 0);
    }
    __syncthreads();  // all reads done before next stage overwrites
  }
  // epilogue: C/D layout col=lane&15, row=(lane>>4)*4+r
  if (MODE == 0) {
    if (z == 2) {
      // V: write transposed (B,H,D,T), packed 4x u16 along T
      u16* O = (u16*)args.out[2];
#pragma unroll
      for (int j = 0; j < 4; ++j) {
        int ncol = n0 + wc * 64 + j * 16 + lr;
        float bj = bias[ncol];
        int hh = ncol >> 6, dd = ncol & 63;
#pragma unroll
        for (int i = 0; i < 4; ++i) {
          int mrow0 = m0 + wr * 64 + i * 16 + lg * 4;
          int bb2 = mrow0 >> 11, tt2 = mrow0 & (Tt - 1);
          s16x4 pk;
#pragma unroll
          for (int r = 0; r < 4; ++r) pk[r] = (short)f2bf(acc[i][j][r] + bj);
          *(s16x4*)&O[(((size_t)bb2 * Hh + hh) * Dd + dd) * Tt + tt2] = pk;
        }
      }
    } else {
      u16* O = (u16*)args.out[z];
#pragma unroll
      for (int j = 0; j < 4; ++j) {
        int ncol = n0 + wc * 64 + j * 16 + lr;
        float bj = bias[ncol];
        int hh = ncol >> 6, dd = ncol & 63;
#pragma unroll
        for (int i = 0; i < 4; ++i) {
#pragma unroll
          for (int r = 0; r < 4; ++r) {
            int mrow = m0 + wr * 64 + i * 16 + lg * 4 + r;
            int bb2 = mrow >> 11, tt2 = mrow & (Tt - 1);
            O[(((size_t)bb2 * Hh + hh) * Tt + tt2) * Dd + dd] = f2bf(acc[i][j][r] + bj);
          }
        }
      }
    }
  } else {
    float* O = (float*)args.out[0];
#pragma unroll
    for (int j = 0; j < 4; ++j) {
      int ncol = n0 + wc * 64 + j * 16 + lr;
      float bj = bias[ncol];
#pragma unroll
      for (int i = 0; i < 4; ++i) {
#pragma unroll
        for (int r = 0; r < 4; ++r) {
          int mrow = m0 + wr * 64 + i * 16 + lg * 4 + r;
          O[(size_t)mrow * Cc + ncol] = acc[i][j][r] + bj;
        }
      }
    }
  }
}

// ---------------- causal flash attention (swapped QK^T, lane-local softmax) ----------------
// KVBLK=128, glds staging of K and VT, log2-domain softmax with defer-max.
// grid (16, B*H), 256 threads; block handles q-tiles {x, 31-x} -> 17 k128-tiles.
__global__ __launch_bounds__(256, 4) void attn_kernel(const u16* __restrict__ Q,
                                                      const u16* __restrict__ K,
                                                      const u16* __restrict__ VTg,
                                                      u16* __restrict__ Out) {
  __shared__ __align__(16) u16 Ks[128 * 64];    // [key][d] swizzled c8^=(key&7)
  __shared__ __align__(16) u16 VTs[64 * 128];   // [d][key] swizzled c8^=(d&7)
  __shared__ __align__(16) u16 Ps[4 * 16 * 32]; // per-wave [q][32key], slot8 = col8 ^ ((q>>1)&3)
  const int tid = threadIdx.x, w = tid >> 6, l = tid & 63;
  const int lr = l & 15, lg = l >> 4;
  const int bh = blockIdx.y;
  const size_t base = (size_t)bh * Tt * Dd;
  const u16* Qp = Q + base;
  const u16* Kp = K + base;
  const u16* Vp = VTg + base;  // (D, T) per bh
  const int bb2 = bh >> 4, hh = bh & 15;
  const float NEG = -3.0e9f;
  f32x4 zero = {0.f, 0.f, 0.f, 0.f};
  // glds lane constants
  const int krow_l = l >> 3, kc8sw = ((l & 7) ^ (l >> 3)) * 8;  // K stage
  const int vrow_l = l >> 4, vc8 = l & 15;                      // VT stage
  const int psw = (lr >> 1) & 3;                                // P swizzle for this lane's q-row

  auto process = [&](int qt) {
    const int qb0 = qt * 64;
    const int qrow = qb0 + w * 16 + lr;
    const int qg = qrow;  // this lane's q index (column of swapped C-frag)
    s16x8 qf[2];
    qf[0] = *(const s16x8*)(Qp + (size_t)qrow * 64 + lg * 8);
    qf[1] = *(const s16x8*)(Qp + (size_t)qrow * 64 + 32 + lg * 8);
    f32x4 o[4] = {zero, zero, zero, zero};
    float m = -3e38f, lsum = 0.f;
    const int ktiles = (qt + 2) >> 1;
    for (int kt = 0; kt < ktiles; ++kt) {
      const int kk0 = kt * 128;
      // ---- stage K[128][64] and VT[64][128] via global_load_lds
#pragma unroll
      for (int i = 0; i < 4; ++i) {
        int krow = i * 32 + w * 8 + krow_l;
        GLDS(Kp + (size_t)(kk0 + krow) * 64 + kc8sw, &Ks[(i * 32 + w * 8) * 64]);
        int d = i * 16 + w * 4 + vrow_l;
        GLDS(Vp + (size_t)d * Tt + kk0 + ((vc8 ^ (d & 7)) * 8), &VTs[(i * 16 + w * 4) * 128]);
      }
      __syncthreads();
      // ---- QK^T swapped: C[key][q]; lane holds keys cf*16+lg*4+r for q=lr
      float pv[8][4];
      const int diag = (kt == ktiles - 1);
      __builtin_amdgcn_s_setprio(1);
#pragma unroll
      for (int cf = 0; cf < 8; ++cf) {
        f32x4 s = zero;
#pragma unroll
        for (int kf = 0; kf < 2; ++kf) {
          s16x8 kb = *(const s16x8*)&Ks[(cf * 16 + lr) * 64 + (((kf * 4 + lg) ^ (lr & 7)) << 3)];
          s = __builtin_amdgcn_mfma_f32_16x16x32_bf16(kb, qf[kf], s, 0, 0, 0);
        }
        if (diag) {
          int key0 = kk0 + cf * 16 + lg * 4;
#pragma unroll
          for (int r = 0; r < 4; ++r) pv[cf][r] = (key0 + r <= qg) ? s[r] : NEG;
        } else {
#pragma unroll
          for (int r = 0; r < 4; ++r) pv[cf][r] = s[r];
        }
      }
      __builtin_amdgcn_s_setprio(0);
      // ---- online softmax: stats lane-local for q = lr
      float t0 = fmaxf(fmaxf(pv[0][0], pv[0][1]), fmaxf(pv[0][2], pv[0][3]));
#pragma unroll
      for (int cf = 1; cf < 8; ++cf) {
        float tc = fmaxf(fmaxf(pv[cf][0], pv[cf][1]), fmaxf(pv[cf][2], pv[cf][3]));
        t0 = fmaxf(t0, tc);
      }
      t0 = fmaxf(t0, __shfl_xor(t0, 16));
      float tm = fmaxf(t0, __shfl_xor(t0, 32));
      int stable = tm <= m + 11.5f;  // defer-max (log2 domain, ~e^8)
      if (!__all(stable)) {
        float mn = fmaxf(m, tm);
        float fsc = exp2f(m - mn);
        lsum *= fsc;
        m = mn;
#pragma unroll
        for (int r = 0; r < 4; ++r) {
          float fr = __shfl(fsc, (l & 48) | (lg * 4 + r));  // stats live at lane lr==q
          o[0][r] *= fr; o[1][r] *= fr; o[2][r] *= fr; o[3][r] *= fr;
        }
      }
      float psum = 0.f;
#pragma unroll
      for (int cf = 0; cf < 8; ++cf)
#pragma unroll
        for (int r = 0; r < 4; ++r) {
          float p = exp2f(pv[cf][r] - m);
          pv[cf][r] = p;
          psum += p;
        }
      psum += __shfl_xor(psum, 16);
      psum += __shfl_xor(psum, 32);
      lsum += psum;
      // ---- PV in 4 chunks of 32 keys: P->LDS [q][key_local], swizzled, then A-frag read
#pragma unroll
      for (int kk = 0; kk < 4; ++kk) {
#pragma unroll
        for (int c = 0; c < 2; ++c) {
#pragma unroll
          for (int r = 0; r < 4; ++r) {
            int col = c * 16 + lg * 4 + r;  // key_local in 0..31
            Ps[w * 512 + lr * 32 + ((((col >> 3) ^ psw)) << 3) + (col & 7)] =
                f2bf(pv[kk * 2 + c][r]);
          }
        }
        s16x8 pa = *(const s16x8*)&Ps[w * 512 + lr * 32 + ((lg ^ psw) << 3)];
        __builtin_amdgcn_s_setprio(1);
#pragma unroll
        for (int jf = 0; jf < 4; ++jf) {
          s16x8 vb = *(const s16x8*)&VTs[(jf * 16 + lr) * 128 + (((kk * 4 + lg) ^ (lr & 7)) << 3)];
          o[jf] = __builtin_amdgcn_mfma_f32_16x16x32_bf16(pa, vb, o[jf], 0, 0, 0);
        }
        __builtin_amdgcn_s_setprio(0);
      }
      __syncthreads();  // all reads done before next stage overwrites
    }
    // ---- epilogue: write (B,T,H*D) bf16; O rows are q = lg*4+r, cols d = jf*16+lr
    float linv = 1.0f / lsum;
#pragma unroll
    for (int r = 0; r < 4; ++r) {
      float lr_inv = __shfl(linv, (l & 48) | (lg * 4 + r));
      int tq = qb0 + w * 16 + lg * 4 + r;
#pragma unroll
      for (int jf = 0; jf < 4; ++jf) {
        Out[((size_t)(bb2 * Tt + tq)) * Cc + hh * 64 + jf * 16 + lr] = f2bf(o[jf][r] * lr_inv);
      }
    }
  };

  process(blockIdx.x);        // light q-tile
  process(31 - blockIdx.x);   // heavy q-tile (total 17 k-tiles, balanced)
}

extern "C" void kernel_launch(void* const* d_in, const int* in_sizes, int n_in,
                              void* d_out, int out_size, void* d_ws, size_t ws_size,
                              hipStream_t stream) {
  (void)in_sizes; (void)n_in; (void)out_size; (void)ws_size;
  const float* x = (const float*)d_in[0];
  const float* Wq = (const float*)d_in[1];
  const float* bq = (const float*)d_in[2];
  const float* Wk = (const float*)d_in[3];
  const float* bk = (const float*)d_in[4];
  const float* Wv = (const float*)d_in[5];
  const float* bv = (const float*)d_in[6];
  const float* Wp = (const float*)d_in[7];
  const float* bp = (const float*)d_in[8];
  const float* rope = (const float*)d_in[9];

  char* ws = (char*)d_ws;
  const size_t MB = 1024 * 1024;
  u16* xb  = (u16*)(ws + 0);        // 16 MB: x as bf16 (8192x1024)
  u16* wqb = (u16*)(ws + 16 * MB);  // 2 MB each
  u16* wkb = (u16*)(ws + 18 * MB);
  u16* wvb = (u16*)(ws + 20 * MB);
  u16* wpb = (u16*)(ws + 22 * MB);
  u16* qb  = (u16*)(ws + 24 * MB);  // 16 MB each; q,k: (B,H,T,D)
  u16* kb  = (u16*)(ws + 40 * MB);
  u16* vt  = (u16*)(ws + 56 * MB);  // V written directly transposed (B,H,D,T)
  u16* att = (u16*)(ws + 72 * MB);  // 16 MB, (B,T,C) bf16 -> ends 88 MB

  cvt_bf16<<<2048, 256, 0, stream>>>(x, xb, (Mm * Cc) / 4);
  Cvt4Args ca;
  ca.s[0] = Wq; ca.s[1] = Wk; ca.s[2] = Wv; ca.s[3] = Wp;
  ca.d[0] = wqb; ca.d[1] = wkb; ca.d[2] = wvb; ca.d[3] = wpb;
  cvt4<<<dim3(256, 4), 256, 0, stream>>>(ca, (Cc * Cc) / 4);

  GemmArgs ga;
  ga.A = xb;
  ga.W[0] = wqb; ga.W[1] = wkb; ga.W[2] = wvb;
  ga.bias[0] = bq; ga.bias[1] = bk; ga.bias[2] = bv;
  ga.out[0] = qb; ga.out[1] = kb; ga.out[2] = vt;  // z=2 writes transposed
  gemm_bt<0><<<dim3(Mm / 128, Cc / 128, 3), 256, 0, stream>>>(ga);

  rope_kernel<<<2048, 256, 0, stream>>>(qb, kb, rope);

  attn_kernel<<<dim3(16, Bb * Hh), 256, 0, stream>>>(qb, kb, vt, att);

  GemmArgs gp;
  gp.A = att;
  gp.W[0] = wpb; gp.W[1] = wpb; gp.W[2] = wpb;
  gp.bias[0] = bp; gp.bias[1] = bp; gp.bias[2] = bp;
  gp.out[0] = d_out; gp.out[1] = d_out; gp.out[2] = d_out;
  gemm_bt<1><<<dim3(Mm / 128, Cc / 128, 1), 256, 0, stream>>>(gp);
}

// Round 5
// 255.181 us; speedup vs baseline: 1.0061x; 1.0061x over previous
//
#include <hip/hip_runtime.h>

#define DEVINL __device__ __forceinline__

typedef unsigned short u16;
typedef __attribute__((ext_vector_type(4))) short s16x4;
typedef __attribute__((ext_vector_type(8))) short s16x8;
typedef __attribute__((ext_vector_type(4))) float f32x4;

static constexpr int Bb = 4, Tt = 2048, Cc = 1024, Hh = 16, Dd = 64;
static constexpr int Mm = Bb * Tt;  // 8192
static constexpr int KK = Cc;       // 1024

DEVINL float bf2f(u16 u) { return __uint_as_float(((unsigned)u) << 16); }
DEVINL u16 f2bf(float f) {
  unsigned b = __float_as_uint(f);
  b += 0x7fff + ((b >> 16) & 1);  // RNE
  return (u16)(b >> 16);
}

#define GLDS(gsrc, ldst) \
  __builtin_amdgcn_global_load_lds((const __attribute__((address_space(1))) void*)(gsrc), \
                                   (__attribute__((address_space(3))) void*)(ldst), 16, 0, 0)

// ---------------- f32 -> bf16 convert (x4 vectorized) ----------------
__global__ void cvt_bf16(const float* __restrict__ src, u16* __restrict__ dst, int n4) {
  int i = blockIdx.x * blockDim.x + threadIdx.x;
  int st = gridDim.x * blockDim.x;
  for (int g = i; g < n4; g += st) {
    float4 v = ((const float4*)src)[g];
    uint2 o;
    o.x = (unsigned)f2bf(v.x) | ((unsigned)f2bf(v.y) << 16);
    o.y = (unsigned)f2bf(v.z) | ((unsigned)f2bf(v.w) << 16);
    ((uint2*)dst)[g] = o;
  }
}

// ---------------- 4 weight converts in one launch ----------------
struct Cvt4Args { const float* s[4]; u16* d[4]; };
__global__ void cvt4(Cvt4Args a, int n4) {
  const float* __restrict__ src = a.s[blockIdx.y];
  u16* __restrict__ dst = a.d[blockIdx.y];
  int i = blockIdx.x * blockDim.x + threadIdx.x;
  int st = gridDim.x * blockDim.x;
  for (int g = i; g < n4; g += st) {
    float4 v = ((const float4*)src)[g];
    uint2 o;
    o.x = (unsigned)f2bf(v.x) | ((unsigned)f2bf(v.y) << 16);
    o.y = (unsigned)f2bf(v.z) | ((unsigned)f2bf(v.w) << 16);
    ((uint2*)dst)[g] = o;
  }
}

// ---------------- RoPE in-place on q,k; Q pre-scaled by 0.125*log2(e) ----------------
__global__ void rope_kernel(u16* __restrict__ q, u16* __restrict__ k,
                            const float* __restrict__ cache) {
  const float CS = 0.18033688f;  // 0.125 * log2(e) folded into Q
  const int total = Bb * Hh * Tt * 8;  // groups of 8 elems
  int i = blockIdx.x * blockDim.x + threadIdx.x;
  int st = gridDim.x * blockDim.x;
  for (int g = i; g < total; g += st) {
    int off = g * 8;
    int t = (off >> 6) & (Tt - 1);
    int d0 = off & 63;
    const float* cp = cache + t * 64 + d0;  // (T, 32, 2) interleaved cos/sin
    float4 c0 = *(const float4*)cp;
    float4 c1 = *(const float4*)(cp + 4);
    float cs[8] = {c0.x, c0.y, c0.z, c0.w, c1.x, c1.y, c1.z, c1.w};
    s16x8 qv = *(s16x8*)(q + off);
    s16x8 kv = *(s16x8*)(k + off);
    s16x8 qo, ko;
#pragma unroll
    for (int p = 0; p < 4; ++p) {
      float c = cs[2 * p], s = cs[2 * p + 1];
      float a = bf2f((u16)qv[2 * p]), b = bf2f((u16)qv[2 * p + 1]);
      qo[2 * p] = (short)f2bf((a * c - b * s) * CS);
      qo[2 * p + 1] = (short)f2bf((a * s + b * c) * CS);
      a = bf2f((u16)kv[2 * p]); b = bf2f((u16)kv[2 * p + 1]);
      ko[2 * p] = (short)f2bf(a * c - b * s);
      ko[2 * p + 1] = (short)f2bf(a * s + b * c);
    }
    *(s16x8*)(q + off) = qo;
    *(s16x8*)(k + off) = ko;
  }
}

// ---------------- bf16 GEMM: out = A(8192x1024) @ W^T + bias ----------------
// glds staging, pre-swizzled source, 2-barrier loop.
// MODE 0: z=0,1 -> bf16 (B,H,T,D); z=2 -> bf16 (B,H,D,T) via LDS-transposed epilogue
// MODE 1: f32 flat (M x C)
struct GemmArgs {
  const u16* A;
  const u16* W[3];
  const float* bias[3];
  void* out[3];
};

template <int MODE>
__global__ __launch_bounds__(256) void gemm_bt(GemmArgs args) {
  __shared__ __align__(16) u16 SM[128 * 128];  // As | Bs, re-aliased as Ts in z=2 epilogue
  u16* As = SM;
  u16* Bs = SM + 128 * 64;
  const int z = blockIdx.z;
  const u16* __restrict__ A = args.A;
  const u16* __restrict__ Wt = args.W[z];
  const float* __restrict__ bias = args.bias[z];
  const int tid = threadIdx.x, w = tid >> 6, l = tid & 63;
  const int lr = l & 15, lg = l >> 4;
  const int m0 = blockIdx.x * 128, n0 = blockIdx.y * 128;
  const int wr = w >> 1, wc = w & 1;
  f32x4 zero = {0.f, 0.f, 0.f, 0.f};
  f32x4 acc[4][4];
#pragma unroll
  for (int i = 0; i < 4; ++i)
#pragma unroll
    for (int j = 0; j < 4; ++j) acc[i][j] = zero;

  // glds staging: LDS slot (row, c8) <- global col8 (c8 ^ (row&7)); row&7 == l>>3
  const int srow = l >> 3;                     // 0..7
  const int scolsw = ((l & 7) ^ (l >> 3)) * 8; // pre-swizzled source col (elems)

  for (int k0 = 0; k0 < KK; k0 += 64) {
#pragma unroll
    for (int i = 0; i < 4; ++i) {
      int row = i * 32 + w * 8 + srow;
      GLDS(A + (size_t)(m0 + row) * KK + k0 + scolsw, &As[(i * 32 + w * 8) * 64]);
      GLDS(Wt + (size_t)(n0 + row) * KK + k0 + scolsw, &Bs[(i * 32 + w * 8) * 64]);
    }
    __syncthreads();  // drains vmcnt -> tiles ready
#pragma unroll
    for (int kk = 0; kk < 2; ++kk) {
      s16x8 af[4], bfr[4];
#pragma unroll
      for (int i = 0; i < 4; ++i)
        af[i] = *(const s16x8*)&As[(wr * 64 + i * 16 + lr) * 64 +
                                   ((kk * 32 + lg * 8) ^ ((lr & 7) << 3))];
#pragma unroll
      for (int j = 0; j < 4; ++j)
        bfr[j] = *(const s16x8*)&Bs[(wc * 64 + j * 16 + lr) * 64 +
                                    ((kk * 32 + lg * 8) ^ ((lr & 7) << 3))];
#pragma unroll
      for (int i = 0; i < 4; ++i)
#pragma unroll
        for (int j = 0; j < 4; ++j)
          acc[i][j] = __builtin_amdgcn_mfma_f32_16x16x32_bf16(af[i], bfr[j], acc[i][j], 0, 0, 0);
    }
    __syncthreads();  // all reads done before next stage overwrites
  }
  // epilogue: C/D layout col=lane&15, row=(lane>>4)*4+r
  if (MODE == 0) {
    if (z == 2) {
      // V: transpose 128x128 tile through LDS (slot4 ^= (ncol&7)<<2), then
      // coalesced 16B stores along T into (B,H,D,T).
      u16* Ts = SM;  // [ncol_local 0..127][mrow_local 0..127]
#pragma unroll
      for (int j = 0; j < 4; ++j) {
        int ncl = wc * 64 + j * 16 + lr;
        float bj = bias[n0 + ncl];
        int xw = (ncl & 7) << 2;
#pragma unroll
        for (int i = 0; i < 4; ++i) {
          int mr4 = wr * 16 + i * 4 + lg;  // mrow_local >> 2
          s16x4 pk;
#pragma unroll
          for (int r = 0; r < 4; ++r) pk[r] = (short)f2bf(acc[i][j][r] + bj);
          *(s16x4*)&Ts[ncl * 128 + ((mr4 ^ xw) << 2)] = pk;
        }
      }
      __syncthreads();
      u16* O = (u16*)args.out[2];
      const int rid = tid >> 4, t8 = tid & 15;
      const int bb2 = m0 >> 11, tloc = m0 & (Tt - 1);
#pragma unroll
      for (int p = 0; p < 8; ++p) {
        int row = p * 16 + rid;  // ncol_local
        int sp = (t8 * 2) ^ ((row & 7) << 2);
        s16x8 v = *(const s16x8*)&Ts[row * 128 + sp * 4];
        int ncol = n0 + row;
        int hh2 = ncol >> 6, dd = ncol & 63;
        *(s16x8*)&O[(((size_t)bb2 * Hh + hh2) * Dd + dd) * Tt + tloc + t8 * 8] = v;
      }
    } else {
      u16* O = (u16*)args.out[z];
#pragma unroll
      for (int j = 0; j < 4; ++j) {
        int ncol = n0 + wc * 64 + j * 16 + lr;
        float bj = bias[ncol];
        int hh = ncol >> 6, dd = ncol & 63;
#pragma unroll
        for (int i = 0; i < 4; ++i) {
#pragma unroll
          for (int r = 0; r < 4; ++r) {
            int mrow = m0 + wr * 64 + i * 16 + lg * 4 + r;
            int bb2 = mrow >> 11, tt2 = mrow & (Tt - 1);
            O[(((size_t)bb2 * Hh + hh) * Tt + tt2) * Dd + dd] = f2bf(acc[i][j][r] + bj);
          }
        }
      }
    }
  } else {
    float* O = (float*)args.out[0];
#pragma unroll
    for (int j = 0; j < 4; ++j) {
      int ncol = n0 + wc * 64 + j * 16 + lr;
      float bj = bias[ncol];
#pragma unroll
      for (int i = 0; i < 4; ++i) {
#pragma unroll
        for (int r = 0; r < 4; ++r) {
          int mrow = m0 + wr * 64 + i * 16 + lg * 4 + r;
          O[(size_t)mrow * Cc + ncol] = acc[i][j][r] + bj;
        }
      }
    }
  }
}

// ---------------- causal flash attention (swapped QK^T, lane-local softmax) ----------------
// KVBLK=128, glds staging of K and VT, log2-domain softmax with defer-max.
// grid (16, B*H), 256 threads; block handles q-tiles {x, 31-x} -> 17 k128-tiles.
__global__ __launch_bounds__(256, 4) void attn_kernel(const u16* __restrict__ Q,
                                                      const u16* __restrict__ K,
                                                      const u16* __restrict__ VTg,
                                                      u16* __restrict__ Out) {
  __shared__ __align__(16) u16 Ks[128 * 64];    // [key][d] swizzled c8^=(key&7)
  __shared__ __align__(16) u16 VTs[64 * 128];   // [d][key] swizzled c8^=(d&7)
  __shared__ __align__(16) u16 Ps[4 * 16 * 32]; // per-wave [q][32key], slot8 = col8 ^ ((q>>1)&3)
  const int tid = threadIdx.x, w = tid >> 6, l = tid & 63;
  const int lr = l & 15, lg = l >> 4;
  const int bh = blockIdx.y;
  const size_t base = (size_t)bh * Tt * Dd;
  const u16* Qp = Q + base;
  const u16* Kp = K + base;
  const u16* Vp = VTg + base;  // (D, T) per bh
  const int bb2 = bh >> 4, hh = bh & 15;
  const float NEG = -3.0e9f;
  f32x4 zero = {0.f, 0.f, 0.f, 0.f};
  // glds lane constants
  const int krow_l = l >> 3, kc8sw = ((l & 7) ^ (l >> 3)) * 8;  // K stage
  const int vrow_l = l >> 4, vc8 = l & 15;                      // VT stage
  const int psw = (lr >> 1) & 3;                                // P swizzle for this lane's q-row

  auto process = [&](int qt) {
    const int qb0 = qt * 64;
    const int qrow = qb0 + w * 16 + lr;
    const int qg = qrow;  // this lane's q index (column of swapped C-frag)
    s16x8 qf[2];
    qf[0] = *(const s16x8*)(Qp + (size_t)qrow * 64 + lg * 8);
    qf[1] = *(const s16x8*)(Qp + (size_t)qrow * 64 + 32 + lg * 8);
    f32x4 o[4] = {zero, zero, zero, zero};
    float m = -3e38f, lsum = 0.f;
    const int ktiles = (qt + 2) >> 1;
    for (int kt = 0; kt < ktiles; ++kt) {
      const int kk0 = kt * 128;
      // ---- stage K[128][64] and VT[64][128] via global_load_lds
#pragma unroll
      for (int i = 0; i < 4; ++i) {
        int krow = i * 32 + w * 8 + krow_l;
        GLDS(Kp + (size_t)(kk0 + krow) * 64 + kc8sw, &Ks[(i * 32 + w * 8) * 64]);
        int d = i * 16 + w * 4 + vrow_l;
        GLDS(Vp + (size_t)d * Tt + kk0 + ((vc8 ^ (d & 7)) * 8), &VTs[(i * 16 + w * 4) * 128]);
      }
      __syncthreads();
      // ---- QK^T swapped: C[key][q]; lane holds keys cf*16+lg*4+r for q=lr
      float pv[8][4];
      const int diag = (kt == ktiles - 1);
      __builtin_amdgcn_s_setprio(1);
#pragma unroll
      for (int cf = 0; cf < 8; ++cf) {
        f32x4 s = zero;
#pragma unroll
        for (int kf = 0; kf < 2; ++kf) {
          s16x8 kb = *(const s16x8*)&Ks[(cf * 16 + lr) * 64 + (((kf * 4 + lg) ^ (lr & 7)) << 3)];
          s = __builtin_amdgcn_mfma_f32_16x16x32_bf16(kb, qf[kf], s, 0, 0, 0);
        }
        if (diag) {
          int key0 = kk0 + cf * 16 + lg * 4;
#pragma unroll
          for (int r = 0; r < 4; ++r) pv[cf][r] = (key0 + r <= qg) ? s[r] : NEG;
        } else {
#pragma unroll
          for (int r = 0; r < 4; ++r) pv[cf][r] = s[r];
        }
      }
      __builtin_amdgcn_s_setprio(0);
      // ---- online softmax: stats lane-local for q = lr
      float t0 = fmaxf(fmaxf(pv[0][0], pv[0][1]), fmaxf(pv[0][2], pv[0][3]));
#pragma unroll
      for (int cf = 1; cf < 8; ++cf) {
        float tc = fmaxf(fmaxf(pv[cf][0], pv[cf][1]), fmaxf(pv[cf][2], pv[cf][3]));
        t0 = fmaxf(t0, tc);
      }
      t0 = fmaxf(t0, __shfl_xor(t0, 16));
      float tm = fmaxf(t0, __shfl_xor(t0, 32));
      int stable = tm <= m + 11.5f;  // defer-max (log2 domain, ~e^8)
      if (!__all(stable)) {
        float mn = fmaxf(m, tm);
        float fsc = exp2f(m - mn);
        lsum *= fsc;
        m = mn;
#pragma unroll
        for (int r = 0; r < 4; ++r) {
          float fr = __shfl(fsc, (l & 48) | (lg * 4 + r));  // stats live at lane lr==q
          o[0][r] *= fr; o[1][r] *= fr; o[2][r] *= fr; o[3][r] *= fr;
        }
      }
      float psum = 0.f;
#pragma unroll
      for (int cf = 0; cf < 8; ++cf)
#pragma unroll
        for (int r = 0; r < 4; ++r) {
          float p = exp2f(pv[cf][r] - m);
          pv[cf][r] = p;
          psum += p;
        }
      psum += __shfl_xor(psum, 16);
      psum += __shfl_xor(psum, 32);
      lsum += psum;
      // ---- PV in 4 chunks of 32 keys: P->LDS [q][key_local], swizzled, then A-frag read
#pragma unroll
      for (int kk = 0; kk < 4; ++kk) {
#pragma unroll
        for (int c = 0; c < 2; ++c) {
#pragma unroll
          for (int r = 0; r < 4; ++r) {
            int col = c * 16 + lg * 4 + r;  // key_local in 0..31
            Ps[w * 512 + lr * 32 + ((((col >> 3) ^ psw)) << 3) + (col & 7)] =
                f2bf(pv[kk * 2 + c][r]);
          }
        }
        s16x8 pa = *(const s16x8*)&Ps[w * 512 + lr * 32 + ((lg ^ psw) << 3)];
        __builtin_amdgcn_s_setprio(1);
#pragma unroll
        for (int jf = 0; jf < 4; ++jf) {
          s16x8 vb = *(const s16x8*)&VTs[(jf * 16 + lr) * 128 + (((kk * 4 + lg) ^ (lr & 7)) << 3)];
          o[jf] = __builtin_amdgcn_mfma_f32_16x16x32_bf16(pa, vb, o[jf], 0, 0, 0);
        }
        __builtin_amdgcn_s_setprio(0);
      }
      __syncthreads();  // all reads done before next stage overwrites
    }
    // ---- epilogue: write (B,T,H*D) bf16; O rows are q = lg*4+r, cols d = jf*16+lr
    float linv = 1.0f / lsum;
#pragma unroll
    for (int r = 0; r < 4; ++r) {
      float lr_inv = __shfl(linv, (l & 48) | (lg * 4 + r));
      int tq = qb0 + w * 16 + lg * 4 + r;
#pragma unroll
      for (int jf = 0; jf < 4; ++jf) {
        Out[((size_t)(bb2 * Tt + tq)) * Cc + hh * 64 + jf * 16 + lr] = f2bf(o[jf][r] * lr_inv);
      }
    }
  };

  process(blockIdx.x);        // light q-tile
  process(31 - blockIdx.x);   // heavy q-tile (total 17 k-tiles, balanced)
}

extern "C" void kernel_launch(void* const* d_in, const int* in_sizes, int n_in,
                              void* d_out, int out_size, void* d_ws, size_t ws_size,
                              hipStream_t stream) {
  (void)in_sizes; (void)n_in; (void)out_size; (void)ws_size;
  const float* x = (const float*)d_in[0];
  const float* Wq = (const float*)d_in[1];
  const float* bq = (const float*)d_in[2];
  const float* Wk = (const float*)d_in[3];
  const float* bk = (const float*)d_in[4];
  const float* Wv = (const float*)d_in[5];
  const float* bv = (const float*)d_in[6];
  const float* Wp = (const float*)d_in[7];
  const float* bp = (const float*)d_in[8];
  const float* rope = (const float*)d_in[9];

  char* ws = (char*)d_ws;
  const size_t MB = 1024 * 1024;
  u16* xb  = (u16*)(ws + 0);        // 16 MB: x as bf16 (8192x1024)
  u16* wqb = (u16*)(ws + 16 * MB);  // 2 MB each
  u16* wkb = (u16*)(ws + 18 * MB);
  u16* wvb = (u16*)(ws + 20 * MB);
  u16* wpb = (u16*)(ws + 22 * MB);
  u16* qb  = (u16*)(ws + 24 * MB);  // 16 MB each; q,k: (B,H,T,D)
  u16* kb  = (u16*)(ws + 40 * MB);
  u16* vt  = (u16*)(ws + 56 * MB);  // V written directly transposed (B,H,D,T)
  u16* att = (u16*)(ws + 72 * MB);  // 16 MB, (B,T,C) bf16 -> ends 88 MB

  cvt_bf16<<<2048, 256, 0, stream>>>(x, xb, (Mm * Cc) / 4);
  Cvt4Args ca;
  ca.s[0] = Wq; ca.s[1] = Wk; ca.s[2] = Wv; ca.s[3] = Wp;
  ca.d[0] = wqb; ca.d[1] = wkb; ca.d[2] = wvb; ca.d[3] = wpb;
  cvt4<<<dim3(256, 4), 256, 0, stream>>>(ca, (Cc * Cc) / 4);

  GemmArgs ga;
  ga.A = xb;
  ga.W[0] = wqb; ga.W[1] = wkb; ga.W[2] = wvb;
  ga.bias[0] = bq; ga.bias[1] = bk; ga.bias[2] = bv;
  ga.out[0] = qb; ga.out[1] = kb; ga.out[2] = vt;  // z=2 writes transposed via LDS
  gemm_bt<0><<<dim3(Mm / 128, Cc / 128, 3), 256, 0, stream>>>(ga);

  rope_kernel<<<2048, 256, 0, stream>>>(qb, kb, rope);

  attn_kernel<<<dim3(16, Bb * Hh), 256, 0, stream>>>(qb, kb, vt, att);

  GemmArgs gp;
  gp.A = att;
  gp.W[0] = wpb; gp.W[1] = wpb; gp.W[2] = wpb;
  gp.bias[0] = bp; gp.bias[1] = bp; gp.bias[2] = bp;
  gp.out[0] = d_out; gp.out[1] = d_out; gp.out[2] = d_out;
  gemm_bt<1><<<dim3(Mm / 128, Cc / 128, 1), 256, 0, stream>>>(gp);
}

// Round 6
// 210.524 us; speedup vs baseline: 1.2196x; 1.2121x over previous
//
#include <hip/hip_runtime.h>

#define DEVINL __device__ __forceinline__

typedef unsigned short u16;
typedef __attribute__((ext_vector_type(4))) short s16x4;
typedef __attribute__((ext_vector_type(8))) short s16x8;
typedef __attribute__((ext_vector_type(4))) float f32x4;

static constexpr int Bb = 4, Tt = 2048, Cc = 1024, Hh = 16, Dd = 64;
static constexpr int Mm = Bb * Tt;  // 8192
static constexpr int KK = Cc;       // 1024

DEVINL float bf2f(u16 u) { return __uint_as_float(((unsigned)u) << 16); }
DEVINL u16 f2bf(float f) {
  unsigned b = __float_as_uint(f);
  b += 0x7fff + ((b >> 16) & 1);  // RNE
  return (u16)(b >> 16);
}

#define GLDS(gsrc, ldst) \
  __builtin_amdgcn_global_load_lds((const __attribute__((address_space(1))) void*)(gsrc), \
                                   (__attribute__((address_space(3))) void*)(ldst), 16, 0, 0)

// ---------------- f32 -> bf16 convert (x4 vectorized) ----------------
__global__ void cvt_bf16(const float* __restrict__ src, u16* __restrict__ dst, int n4) {
  int i = blockIdx.x * blockDim.x + threadIdx.x;
  int st = gridDim.x * blockDim.x;
  for (int g = i; g < n4; g += st) {
    float4 v = ((const float4*)src)[g];
    uint2 o;
    o.x = (unsigned)f2bf(v.x) | ((unsigned)f2bf(v.y) << 16);
    o.y = (unsigned)f2bf(v.z) | ((unsigned)f2bf(v.w) << 16);
    ((uint2*)dst)[g] = o;
  }
}

// ---------------- 4 weight converts in one launch ----------------
struct Cvt4Args { const float* s[4]; u16* d[4]; };
__global__ void cvt4(Cvt4Args a, int n4) {
  const float* __restrict__ src = a.s[blockIdx.y];
  u16* __restrict__ dst = a.d[blockIdx.y];
  int i = blockIdx.x * blockDim.x + threadIdx.x;
  int st = gridDim.x * blockDim.x;
  for (int g = i; g < n4; g += st) {
    float4 v = ((const float4*)src)[g];
    uint2 o;
    o.x = (unsigned)f2bf(v.x) | ((unsigned)f2bf(v.y) << 16);
    o.y = (unsigned)f2bf(v.z) | ((unsigned)f2bf(v.w) << 16);
    ((uint2*)dst)[g] = o;
  }
}

// ---------------- RoPE in-place on q,k; Q pre-scaled by 0.125*log2(e) ----------------
__global__ void rope_kernel(u16* __restrict__ q, u16* __restrict__ k,
                            const float* __restrict__ cache) {
  const float CS = 0.18033688f;  // 0.125 * log2(e) folded into Q
  const int total = Bb * Hh * Tt * 8;  // groups of 8 elems
  int i = blockIdx.x * blockDim.x + threadIdx.x;
  int st = gridDim.x * blockDim.x;
  for (int g = i; g < total; g += st) {
    int off = g * 8;
    int t = (off >> 6) & (Tt - 1);
    int d0 = off & 63;
    const float* cp = cache + t * 64 + d0;  // (T, 32, 2) interleaved cos/sin
    float4 c0 = *(const float4*)cp;
    float4 c1 = *(const float4*)(cp + 4);
    float cs[8] = {c0.x, c0.y, c0.z, c0.w, c1.x, c1.y, c1.z, c1.w};
    s16x8 qv = *(s16x8*)(q + off);
    s16x8 kv = *(s16x8*)(k + off);
    s16x8 qo, ko;
#pragma unroll
    for (int p = 0; p < 4; ++p) {
      float c = cs[2 * p], s = cs[2 * p + 1];
      float a = bf2f((u16)qv[2 * p]), b = bf2f((u16)qv[2 * p + 1]);
      qo[2 * p] = (short)f2bf((a * c - b * s) * CS);
      qo[2 * p + 1] = (short)f2bf((a * s + b * c) * CS);
      a = bf2f((u16)kv[2 * p]); b = bf2f((u16)kv[2 * p + 1]);
      ko[2 * p] = (short)f2bf(a * c - b * s);
      ko[2 * p + 1] = (short)f2bf(a * s + b * c);
    }
    *(s16x8*)(q + off) = qo;
    *(s16x8*)(k + off) = ko;
  }
}

// ---- shared K-loop for all GEMMs: fixed __shared__ As/Bs, glds staging ----
#define GEMM_PROLOG()                                              \
  const int tid = threadIdx.x, w = tid >> 6, l = tid & 63;         \
  const int lr = l & 15, lg = l >> 4;                              \
  const int m0 = blockIdx.x * 128, n0 = blockIdx.y * 128;          \
  const int wr = w >> 1, wc = w & 1;                               \
  f32x4 zero = {0.f, 0.f, 0.f, 0.f};                               \
  f32x4 acc[4][4];                                                 \
  _Pragma("unroll") for (int i = 0; i < 4; ++i)                    \
      _Pragma("unroll") for (int j = 0; j < 4; ++j) acc[i][j] = zero; \
  const int srow = l >> 3;                                         \
  const int scolsw = ((l & 7) ^ (l >> 3)) * 8;

#define GEMM_KLOOP(Aptr, Wptr)                                                         \
  for (int k0 = 0; k0 < KK; k0 += 64) {                                                \
    _Pragma("unroll") for (int i = 0; i < 4; ++i) {                                    \
      int row = i * 32 + w * 8 + srow;                                                 \
      GLDS(Aptr + (size_t)(m0 + row) * KK + k0 + scolsw, &As[(i * 32 + w * 8) * 64]);  \
      GLDS(Wptr + (size_t)(n0 + row) * KK + k0 + scolsw, &Bs[(i * 32 + w * 8) * 64]);  \
    }                                                                                  \
    __syncthreads();                                                                   \
    _Pragma("unroll") for (int kk = 0; kk < 2; ++kk) {                                 \
      s16x8 af[4], bfr[4];                                                             \
      _Pragma("unroll") for (int i = 0; i < 4; ++i)                                    \
          af[i] = *(const s16x8*)&As[(wr * 64 + i * 16 + lr) * 64 +                    \
                                     ((kk * 32 + lg * 8) ^ ((lr & 7) << 3))];          \
      _Pragma("unroll") for (int j = 0; j < 4; ++j)                                    \
          bfr[j] = *(const s16x8*)&Bs[(wc * 64 + j * 16 + lr) * 64 +                   \
                                      ((kk * 32 + lg * 8) ^ ((lr & 7) << 3))];         \
      _Pragma("unroll") for (int i = 0; i < 4; ++i)                                    \
          _Pragma("unroll") for (int j = 0; j < 4; ++j)                                \
              acc[i][j] =                                                              \
                  __builtin_amdgcn_mfma_f32_16x16x32_bf16(af[i], bfr[j], acc[i][j], 0, 0, 0); \
    }                                                                                  \
    __syncthreads();                                                                   \
  }

// ---------------- Q/K GEMM: z selects {q,k}; out bf16 (B,H,T,D) ----------------
__global__ __launch_bounds__(256) void gemm_qk(const u16* __restrict__ A,
                                               const u16* __restrict__ W0,
                                               const u16* __restrict__ W1,
                                               const float* __restrict__ b0,
                                               const float* __restrict__ b1,
                                               u16* __restrict__ O0, u16* __restrict__ O1) {
  __shared__ __align__(16) u16 As[128 * 64];
  __shared__ __align__(16) u16 Bs[128 * 64];
  const int z = blockIdx.z;
  const u16* __restrict__ Wt = z ? W1 : W0;
  const float* __restrict__ bias = z ? b1 : b0;
  u16* __restrict__ O = z ? O1 : O0;
  GEMM_PROLOG()
  GEMM_KLOOP(A, Wt)
#pragma unroll
  for (int j = 0; j < 4; ++j) {
    int ncol = n0 + wc * 64 + j * 16 + lr;
    float bj = bias[ncol];
    int hh = ncol >> 6, dd = ncol & 63;
#pragma unroll
    for (int i = 0; i < 4; ++i) {
#pragma unroll
      for (int r = 0; r < 4; ++r) {
        int mrow = m0 + wr * 64 + i * 16 + lg * 4 + r;
        int bb2 = mrow >> 11, tt2 = mrow & (Tt - 1);
        O[(((size_t)bb2 * Hh + hh) * Tt + tt2) * Dd + dd] = f2bf(acc[i][j][r] + bj);
      }
    }
  }
}

// ---------------- V GEMM: out bf16 (B,H,D,T) via two-pass LDS transpose ----------------
__global__ __launch_bounds__(256) void gemm_v(const u16* __restrict__ A,
                                              const u16* __restrict__ Wt,
                                              const float* __restrict__ bias,
                                              u16* __restrict__ O) {
  __shared__ __align__(16) u16 As[128 * 64];
  __shared__ __align__(16) u16 Bs[128 * 64];
  __shared__ __align__(16) u16 Ts[128 * 64];  // [ncol_local][mrow_half], slot4-XOR swizzled
  GEMM_PROLOG()
  GEMM_KLOOP(A, Wt)
  const int bb2 = m0 >> 11, tloc = m0 & (Tt - 1);
#pragma unroll
  for (int p = 0; p < 2; ++p) {
    if (p) __syncthreads();
    if (wr == p) {
#pragma unroll
      for (int j = 0; j < 4; ++j) {
        int ncl = wc * 64 + j * 16 + lr;
        float bj = bias[n0 + ncl];
        int xw = (ncl & 3) << 2;
#pragma unroll
        for (int i = 0; i < 4; ++i) {
          s16x4 pk;
#pragma unroll
          for (int r = 0; r < 4; ++r) pk[r] = (short)f2bf(acc[i][j][r] + bj);
          *(s16x4*)&Ts[ncl * 64 + (((i * 4 + lg) ^ xw) << 2)] = pk;
        }
      }
    }
    __syncthreads();
    // all threads: read Ts and store coalesced along T (128B per row-half)
    const int rn = tid >> 3, t8 = tid & 7;
#pragma unroll
    for (int it = 0; it < 4; ++it) {
      int rown = it * 32 + rn;  // ncol_local
      int slot = (t8 * 2) ^ ((rown & 3) << 2);
      s16x8 v = *(const s16x8*)&Ts[rown * 64 + slot * 4];
      int ncol = n0 + rown;
      int hh2 = ncol >> 6, dd = ncol & 63;
      *(s16x8*)&O[(((size_t)bb2 * Hh + hh2) * Dd + dd) * Tt + tloc + p * 64 + t8 * 8] = v;
    }
  }
}

// ---------------- projection GEMM: out f32 flat (M x C) ----------------
__global__ __launch_bounds__(256) void gemm_proj(const u16* __restrict__ A,
                                                 const u16* __restrict__ Wt,
                                                 const float* __restrict__ bias,
                                                 float* __restrict__ O) {
  __shared__ __align__(16) u16 As[128 * 64];
  __shared__ __align__(16) u16 Bs[128 * 64];
  GEMM_PROLOG()
  GEMM_KLOOP(A, Wt)
#pragma unroll
  for (int j = 0; j < 4; ++j) {
    int ncol = n0 + wc * 64 + j * 16 + lr;
    float bj = bias[ncol];
#pragma unroll
    for (int i = 0; i < 4; ++i) {
#pragma unroll
      for (int r = 0; r < 4; ++r) {
        int mrow = m0 + wr * 64 + i * 16 + lg * 4 + r;
        O[(size_t)mrow * Cc + ncol] = acc[i][j][r] + bj;
      }
    }
  }
}

// ---------------- causal flash attention (swapped QK^T, lane-local softmax) ----------------
// KVBLK=128, glds staging of K and VT, log2-domain softmax with defer-max.
// grid (16, B*H), 256 threads; block handles q-tiles {x, 31-x} -> 17 k128-tiles.
__global__ __launch_bounds__(256, 4) void attn_kernel(const u16* __restrict__ Q,
                                                      const u16* __restrict__ K,
                                                      const u16* __restrict__ VTg,
                                                      u16* __restrict__ Out) {
  __shared__ __align__(16) u16 Ks[128 * 64];    // [key][d] swizzled c8^=(key&7)
  __shared__ __align__(16) u16 VTs[64 * 128];   // [d][key] swizzled c8^=(d&7)
  __shared__ __align__(16) u16 Ps[4 * 16 * 32]; // per-wave [q][32key], slot8 = col8 ^ ((q>>1)&3)
  const int tid = threadIdx.x, w = tid >> 6, l = tid & 63;
  const int lr = l & 15, lg = l >> 4;
  const int bh = blockIdx.y;
  const size_t base = (size_t)bh * Tt * Dd;
  const u16* Qp = Q + base;
  const u16* Kp = K + base;
  const u16* Vp = VTg + base;  // (D, T) per bh
  const int bb2 = bh >> 4, hh = bh & 15;
  const float NEG = -3.0e9f;
  f32x4 zero = {0.f, 0.f, 0.f, 0.f};
  const int krow_l = l >> 3, kc8sw = ((l & 7) ^ (l >> 3)) * 8;  // K stage
  const int vrow_l = l >> 4, vc8 = l & 15;                      // VT stage
  const int psw = (lr >> 1) & 3;                                // P swizzle for this lane's q-row

  auto process = [&](int qt) {
    const int qb0 = qt * 64;
    const int qrow = qb0 + w * 16 + lr;
    const int qg = qrow;
    s16x8 qf[2];
    qf[0] = *(const s16x8*)(Qp + (size_t)qrow * 64 + lg * 8);
    qf[1] = *(const s16x8*)(Qp + (size_t)qrow * 64 + 32 + lg * 8);
    f32x4 o[4] = {zero, zero, zero, zero};
    float m = -3e38f, lsum = 0.f;
    const int ktiles = (qt + 2) >> 1;
    for (int kt = 0; kt < ktiles; ++kt) {
      const int kk0 = kt * 128;
#pragma unroll
      for (int i = 0; i < 4; ++i) {
        int krow = i * 32 + w * 8 + krow_l;
        GLDS(Kp + (size_t)(kk0 + krow) * 64 + kc8sw, &Ks[(i * 32 + w * 8) * 64]);
        int d = i * 16 + w * 4 + vrow_l;
        GLDS(Vp + (size_t)d * Tt + kk0 + ((vc8 ^ (d & 7)) * 8), &VTs[(i * 16 + w * 4) * 128]);
      }
      __syncthreads();
      // ---- QK^T swapped: C[key][q]; lane holds keys cf*16+lg*4+r for q=lr
      float pv[8][4];
      const int diag = (kt == ktiles - 1);
      __builtin_amdgcn_s_setprio(1);
#pragma unroll
      for (int cf = 0; cf < 8; ++cf) {
        f32x4 s = zero;
#pragma unroll
        for (int kf = 0; kf < 2; ++kf) {
          s16x8 kb = *(const s16x8*)&Ks[(cf * 16 + lr) * 64 + (((kf * 4 + lg) ^ (lr & 7)) << 3)];
          s = __builtin_amdgcn_mfma_f32_16x16x32_bf16(kb, qf[kf], s, 0, 0, 0);
        }
        if (diag) {
          int key0 = kk0 + cf * 16 + lg * 4;
#pragma unroll
          for (int r = 0; r < 4; ++r) pv[cf][r] = (key0 + r <= qg) ? s[r] : NEG;
        } else {
#pragma unroll
          for (int r = 0; r < 4; ++r) pv[cf][r] = s[r];
        }
      }
      __builtin_amdgcn_s_setprio(0);
      // ---- online softmax: stats lane-local for q = lr
      float t0 = fmaxf(fmaxf(pv[0][0], pv[0][1]), fmaxf(pv[0][2], pv[0][3]));
#pragma unroll
      for (int cf = 1; cf < 8; ++cf) {
        float tc = fmaxf(fmaxf(pv[cf][0], pv[cf][1]), fmaxf(pv[cf][2], pv[cf][3]));
        t0 = fmaxf(t0, tc);
      }
      t0 = fmaxf(t0, __shfl_xor(t0, 16));
      float tm = fmaxf(t0, __shfl_xor(t0, 32));
      int stable = tm <= m + 11.5f;  // defer-max (log2 domain, ~e^8)
      if (!__all(stable)) {
        float mn = fmaxf(m, tm);
        float fsc = exp2f(m - mn);
        lsum *= fsc;
        m = mn;
#pragma unroll
        for (int r = 0; r < 4; ++r) {
          float fr = __shfl(fsc, (l & 48) | (lg * 4 + r));  // stats live at lane lr==q
          o[0][r] *= fr; o[1][r] *= fr; o[2][r] *= fr; o[3][r] *= fr;
        }
      }
      float psum = 0.f;
#pragma unroll
      for (int cf = 0; cf < 8; ++cf)
#pragma unroll
        for (int r = 0; r < 4; ++r) {
          float p = exp2f(pv[cf][r] - m);
          pv[cf][r] = p;
          psum += p;
        }
      psum += __shfl_xor(psum, 16);
      psum += __shfl_xor(psum, 32);
      lsum += psum;
      // ---- PV in 4 chunks of 32 keys: P->LDS [q][key_local], swizzled, then A-frag read
#pragma unroll
      for (int kk = 0; kk < 4; ++kk) {
#pragma unroll
        for (int c = 0; c < 2; ++c) {
#pragma unroll
          for (int r = 0; r < 4; ++r) {
            int col = c * 16 + lg * 4 + r;  // key_local in 0..31
            Ps[w * 512 + lr * 32 + ((((col >> 3) ^ psw)) << 3) + (col & 7)] =
                f2bf(pv[kk * 2 + c][r]);
          }
        }
        s16x8 pa = *(const s16x8*)&Ps[w * 512 + lr * 32 + ((lg ^ psw) << 3)];
        __builtin_amdgcn_s_setprio(1);
#pragma unroll
        for (int jf = 0; jf < 4; ++jf) {
          s16x8 vb = *(const s16x8*)&VTs[(jf * 16 + lr) * 128 + (((kk * 4 + lg) ^ (lr & 7)) << 3)];
          o[jf] = __builtin_amdgcn_mfma_f32_16x16x32_bf16(pa, vb, o[jf], 0, 0, 0);
        }
        __builtin_amdgcn_s_setprio(0);
      }
      __syncthreads();  // all reads done before next stage overwrites
    }
    // ---- epilogue: write (B,T,H*D) bf16; O rows are q = lg*4+r, cols d = jf*16+lr
    float linv = 1.0f / lsum;
#pragma unroll
    for (int r = 0; r < 4; ++r) {
      float lr_inv = __shfl(linv, (l & 48) | (lg * 4 + r));
      int tq = qb0 + w * 16 + lg * 4 + r;
#pragma unroll
      for (int jf = 0; jf < 4; ++jf) {
        Out[((size_t)(bb2 * Tt + tq)) * Cc + hh * 64 + jf * 16 + lr] = f2bf(o[jf][r] * lr_inv);
      }
    }
  };

  process(blockIdx.x);        // light q-tile
  process(31 - blockIdx.x);   // heavy q-tile (total 17 k-tiles, balanced)
}

extern "C" void kernel_launch(void* const* d_in, const int* in_sizes, int n_in,
                              void* d_out, int out_size, void* d_ws, size_t ws_size,
                              hipStream_t stream) {
  (void)in_sizes; (void)n_in; (void)out_size; (void)ws_size;
  const float* x = (const float*)d_in[0];
  const float* Wq = (const float*)d_in[1];
  const float* bq = (const float*)d_in[2];
  const float* Wk = (const float*)d_in[3];
  const float* bk = (const float*)d_in[4];
  const float* Wv = (const float*)d_in[5];
  const float* bv = (const float*)d_in[6];
  const float* Wp = (const float*)d_in[7];
  const float* bp = (const float*)d_in[8];
  const float* rope = (const float*)d_in[9];

  char* ws = (char*)d_ws;
  const size_t MB = 1024 * 1024;
  u16* xb  = (u16*)(ws + 0);        // 16 MB: x as bf16 (8192x1024)
  u16* wqb = (u16*)(ws + 16 * MB);  // 2 MB each
  u16* wkb = (u16*)(ws + 18 * MB);
  u16* wvb = (u16*)(ws + 20 * MB);
  u16* wpb = (u16*)(ws + 22 * MB);
  u16* qb  = (u16*)(ws + 24 * MB);  // 16 MB each; q,k: (B,H,T,D)
  u16* kb  = (u16*)(ws + 40 * MB);
  u16* vt  = (u16*)(ws + 56 * MB);  // V written directly transposed (B,H,D,T)
  u16* att = (u16*)(ws + 72 * MB);  // 16 MB, (B,T,C) bf16 -> ends 88 MB

  cvt_bf16<<<2048, 256, 0, stream>>>(x, xb, (Mm * Cc) / 4);
  Cvt4Args ca;
  ca.s[0] = Wq; ca.s[1] = Wk; ca.s[2] = Wv; ca.s[3] = Wp;
  ca.d[0] = wqb; ca.d[1] = wkb; ca.d[2] = wvb; ca.d[3] = wpb;
  cvt4<<<dim3(256, 4), 256, 0, stream>>>(ca, (Cc * Cc) / 4);

  gemm_qk<<<dim3(Mm / 128, Cc / 128, 2), 256, 0, stream>>>(xb, wqb, wkb, bq, bk, qb, kb);
  gemm_v<<<dim3(Mm / 128, Cc / 128), 256, 0, stream>>>(xb, wvb, bv, vt);

  rope_kernel<<<2048, 256, 0, stream>>>(qb, kb, rope);

  attn_kernel<<<dim3(16, Bb * Hh), 256, 0, stream>>>(qb, kb, vt, att);

  gemm_proj<<<dim3(Mm / 128, Cc / 128), 256, 0, stream>>>(att, wpb, bp, (float*)d_out);
}